// Round 5
// baseline (802.570 us; speedup 1.0000x reference)
//
#include <hip/hip_runtime.h>

// CausalAttention2d: B=2, C=512, H=W=64 (N=4096 tokens), E=512, nh=8, hd=64.
// Inputs fp32 (runtime-detected; bf16 path kept defensively). Pipeline:
//   detect -> wcvt (W,b -> bf16) -> transpose -> gemm x3 -> flash attn.
// Round 5: attn rewritten with ZERO LDS and zero barriers. S^T = K*Q^T
// (A=K, B=Q, both global-direct b128); S^T's C-layout (col=q, rows=key
// quad*4+r) is exactly the B-operand footprint of mfma_16x16x16bf16_1k,
// so P^T feeds PV straight from registers (exp2 + pack, no shuffles).
// PV: A = V^T direct b64 from e-major V. O^T epilogue: one 1/l per lane.

typedef __bf16 bf16;
typedef __attribute__((ext_vector_type(8))) __bf16 bf16x8;
typedef __attribute__((ext_vector_type(4))) __bf16 bf16x4;
typedef __attribute__((ext_vector_type(4))) short short4v;
typedef __attribute__((ext_vector_type(4))) float floatx4;

#define B_ 2
#define Cc 512
#define Nn 4096
#define Ee 512
#define NH 8
#define HD 64

#define QSCALE 0.1803368801111204f   // log2(e)/8, folded into Q
#define SHIFT 11.541560327111707f    // 8*log2(e): p = 2^(s - SHIFT)

// ---------------------------------------------------------------- detector
// One wave. flag=1 -> inputs are fp32; flag=0 -> inputs are bf16.
__global__ __launch_bounds__(64) void detect_dtype(
    const unsigned short* __restrict__ w, int* __restrict__ flag) {
  bool bad = false;
#pragma unroll
  for (int i = 0; i < 16; ++i) {
    unsigned u = w[threadIdx.x * 16 + i];
    float v = __uint_as_float(u << 16);
    bad |= !(v > -1024.f && v < 1024.f);  // catches big / inf / NaN
  }
  unsigned long long b = __ballot(bad);
  if (threadIdx.x == 0) *flag = (b != 0ull) ? 1 : 0;
}

// ---------------------------------------------------------------- wcvt
// fp32 -> bf16 conversion of Wq,Wk,Wv,bq,bk,bv into one packed region.
// Only runs when flag=1 (region lives in d_out's upper half, fp32-only).
#define WSEG 262144          // 512*512
#define WTOT 787968          // 3*WSEG + 3*512
__global__ __launch_bounds__(256) void wcvt(
    const float* __restrict__ Wq, const float* __restrict__ Wk,
    const float* __restrict__ Wv, const float* __restrict__ bq,
    const float* __restrict__ bk, const float* __restrict__ bv,
    bf16* __restrict__ out, const int* __restrict__ flagp) {
  if (!*flagp) return;
  int idx = (blockIdx.x * 256 + threadIdx.x) * 8;
  if (idx >= WTOT) return;
  const float* src;
  int off;
  if (idx < WSEG)            { src = Wq; off = idx; }
  else if (idx < 2 * WSEG)   { src = Wk; off = idx - WSEG; }
  else if (idx < 3 * WSEG)   { src = Wv; off = idx - 2 * WSEG; }
  else if (idx < 3 * WSEG + 512)  { src = bq; off = idx - 3 * WSEG; }
  else if (idx < 3 * WSEG + 1024) { src = bk; off = idx - 3 * WSEG - 512; }
  else                            { src = bv; off = idx - 3 * WSEG - 1024; }
  float4 a = *(const float4*)(src + off);
  float4 c = *(const float4*)(src + off + 4);
  union { bf16 h[8]; bf16x8 v; } u;
  u.h[0] = (bf16)a.x; u.h[1] = (bf16)a.y; u.h[2] = (bf16)a.z; u.h[3] = (bf16)a.w;
  u.h[4] = (bf16)c.x; u.h[5] = (bf16)c.y; u.h[6] = (bf16)c.z; u.h[7] = (bf16)c.w;
  *(bf16x8*)(out + idx) = u.v;
}

// load 8 consecutive elements as bf16x8 from bf16 (f32=0) or fp32 (f32=1).
__device__ __forceinline__ bf16x8 load8e(const void* base, size_t eidx, int f32) {
  if (!f32) return *(const bf16x8*)((const bf16*)base + eidx);
  const float* f = (const float*)base + eidx;
  float4 a = *(const float4*)f;
  float4 c = *(const float4*)(f + 4);
  union { bf16 h[8]; bf16x8 v; } u;
  u.h[0] = (bf16)a.x; u.h[1] = (bf16)a.y; u.h[2] = (bf16)a.z; u.h[3] = (bf16)a.w;
  u.h[4] = (bf16)c.x; u.h[5] = (bf16)c.y; u.h[6] = (bf16)c.z; u.h[7] = (bf16)c.w;
  return u.v;
}

// ---------------------------------------------------------------- transpose
// (B,C,N) -> (B,N,C) for query and key; output always bf16 token-major.
__global__ __launch_bounds__(256) void transpose_k(
    const void* __restrict__ X0, const void* __restrict__ X1,
    bf16* __restrict__ T0, bf16* __restrict__ T1,
    const int* __restrict__ flagp) {
  const int f32 = *flagp;
  __shared__ __align__(16) bf16 T[64 * 64];
  const int z = blockIdx.z;
  const int bb = z & 1;
  const void* src = (z >> 1) ? X1 : X0;
  bf16* dst = (z >> 1) ? T1 : T0;
  const int n0 = blockIdx.x * 64, c0 = blockIdx.y * 64;
  const int t = threadIdx.x;
  const size_t sbase = ((size_t)bb * Cc + c0) * (size_t)Nn + n0;

#pragma unroll
  for (int it = 0; it < 2; ++it) {
    int task = t + it * 256;            // 512 tasks: 64 c-rows x 8 n-granules
    int crow = task >> 3, gr = task & 7;
    bf16x8 v = load8e(src, sbase + (size_t)crow * Nn + gr * 8, f32);
    int slot = gr ^ (crow & 7);
    *(bf16x8*)&T[crow * 64 + slot * 8] = v;
  }
  __syncthreads();
  const int nrow = t & 63, cp = t >> 6;
  bf16* db = dst + ((size_t)bb * Nn + n0 + nrow) * Cc + c0;
#pragma unroll
  for (int it = 0; it < 2; ++it) {
    int cg = cp * 2 + it;               // c-granule 0..7
    union { bf16 h[8]; bf16x8 v; } u;
#pragma unroll
    for (int j = 0; j < 8; ++j) {
      int c = cg * 8 + j;
      int slot = (nrow >> 3) ^ (c & 7);
      u.h[j] = T[c * 64 + slot * 8 + (nrow & 7)];
    }
    *(bf16x8*)(db + cg * 8) = u.v;
  }
}

// ---------------------------------------------------------------- gemm_bt
// Out[m][n] = (sum_k A[m][k]*Bt[n][k] + bias) * scaleOut.
// Operand pointers: (P0, P1) -> use P1 when flag=1 (bf16-converted W),
// P0 when flag=0 (original bf16). ws operands pass the same ptr twice.
// Tile 128(m) x 64(n) x BK=32, 4 waves, 16x16x32 bf16 MFMA, stride-40 LDS.
__global__ __launch_bounds__(256) void gemm_bt(
    const void* __restrict__ A0, const bf16* __restrict__ A1, long sAb,
    const void* __restrict__ B0, const bf16* __restrict__ B1, long sBb,
    const void* __restrict__ bias0, const bf16* __restrict__ bias1,
    bf16* __restrict__ Out, long sOb,
    int Nq, int biasOnM, float scaleOut, const int* __restrict__ flagp) {
  const int f32 = *flagp;
  const bf16* A = f32 ? A1 : (const bf16*)A0;
  const bf16* Bt = f32 ? B1 : (const bf16*)B0;
  const bf16* bias = f32 ? bias1 : (const bf16*)bias0;
  constexpr int K = 512;
  constexpr int SA = 40;  // padded stride (80B, 16B-aligned)
  __shared__ __align__(16) bf16 As[128 * SA];
  __shared__ __align__(16) bf16 Bs[64 * SA];
  const int tid = threadIdx.x;
  const int lane = tid & 63, wave = tid >> 6;
  const int quad = lane >> 4, lm = lane & 15;
  const int m0 = blockIdx.x * 128, n0 = blockIdx.y * 64;
  const int b = blockIdx.z;
  const bf16* Ab = A + (size_t)b * sAb;
  const bf16* Bb = Bt + (size_t)b * sBb;
  bf16* Ob = Out + (size_t)b * sOb;

  const int arow = tid >> 2, ag = tid & 3;  // staging task split

  floatx4 acc[2][4];
#pragma unroll
  for (int i = 0; i < 2; ++i)
#pragma unroll
    for (int j = 0; j < 4; ++j) acc[i][j] = (floatx4){0.f, 0.f, 0.f, 0.f};

  for (int k0 = 0; k0 < K; k0 += 32) {
    bf16x8 a0 = *(const bf16x8*)(Ab + (size_t)(m0 + arow) * K + k0 + ag * 8);
    bf16x8 a1 = *(const bf16x8*)(Ab + (size_t)(m0 + 64 + arow) * K + k0 + ag * 8);
    bf16x8 b0 = *(const bf16x8*)(Bb + (size_t)(n0 + arow) * K + k0 + ag * 8);
    __syncthreads();  // previous iteration's LDS reads complete
    *(bf16x8*)&As[arow * SA + ag * 8] = a0;
    *(bf16x8*)&As[(64 + arow) * SA + ag * 8] = a1;
    *(bf16x8*)&Bs[arow * SA + ag * 8] = b0;
    __syncthreads();  // staging complete

    bf16x8 af[2], bfr[4];
#pragma unroll
    for (int mf = 0; mf < 2; ++mf) {
      int r = wave * 32 + mf * 16 + lm;
      af[mf] = *(const bf16x8*)&As[r * SA + quad * 8];
    }
#pragma unroll
    for (int nf = 0; nf < 4; ++nf) {
      int r = nf * 16 + lm;
      bfr[nf] = *(const bf16x8*)&Bs[r * SA + quad * 8];
    }
#pragma unroll
    for (int mf = 0; mf < 2; ++mf)
#pragma unroll
      for (int nf = 0; nf < 4; ++nf)
        acc[mf][nf] = __builtin_amdgcn_mfma_f32_16x16x32_bf16(
            af[mf], bfr[nf], acc[mf][nf], 0, 0, 0);
  }

  // epilogue: C layout col=lane&15, row=quad*4+reg
#pragma unroll
  for (int mf = 0; mf < 2; ++mf) {
#pragma unroll
    for (int nf = 0; nf < 4; ++nf) {
      int col = n0 + nf * 16 + lm;
      float bn = biasOnM ? 0.f : (float)bias[col];
#pragma unroll
      for (int r = 0; r < 4; ++r) {
        int rowg = m0 + wave * 32 + mf * 16 + quad * 4 + r;
        float bv = biasOnM ? (float)bias[rowg] : bn;
        Ob[(size_t)rowg * Nq + col] = (bf16)((acc[mf][nf][r] + bv) * scaleOut);
      }
    }
  }
}

// ---------------------------------------------------------------- attention
// Per (b, head): 1024 blocks x 256 thr; wave w owns 16 q-rows. ZERO LDS,
// zero barriers. Per 64-key tile:
//   S^T[key][q] = K*Q^T via mfma_16x16x32 (A=K global b128, B=Q held in reg)
//   p = 2^(s-SHIFT) (+causal), packed in-lane to bf16x4 = exact B-frag of
//   mfma_16x16x16bf16_1k (B[k=quad*4+j][n=lm])
//   O^T[d][q] += V^T * P^T via 1k MFMA (A = V^T global b64)
// Epilogue: O^T C-layout -> all 4 regs share col q -> single 1/l per lane.
__global__ __launch_bounds__(256, 4) void attn(
    const bf16* __restrict__ Qt, const bf16* __restrict__ Kt,
    const bf16* __restrict__ Ve, void* __restrict__ Out,
    const int* __restrict__ flagp) {
  const int f32 = *flagp;
  const int tid = threadIdx.x, lane = tid & 63, w = tid >> 6;
  const int quad = lane >> 4, lm = lane & 15;
  const int qt = 63 - (int)blockIdx.x;  // heavy tiles dispatch first
  const int h = blockIdx.y, b = blockIdx.z;
  const int n0 = qt * 64;
  const int qglob = n0 + w * 16 + lm;

  // Q B-frag (persistent): B[e=quad*8+j (+32*ks)][q=lm]
  bf16x8 qf[2];
  {
    const bf16* qp = Qt + ((size_t)b * Nn + qglob) * Ee + h * HD + quad * 8;
    qf[0] = *(const bf16x8*)qp;
    qf[1] = *(const bf16x8*)(qp + 32);
  }
  floatx4 accO[4];
#pragma unroll
  for (int df = 0; df < 4; ++df) accO[df] = (floatx4){0.f, 0.f, 0.f, 0.f};
  float lsum = 0.f;

  const bf16* kr = Kt + ((size_t)b * Nn + lm) * Ee + h * HD + quad * 8;
  const bf16* vr = Ve + ((size_t)b * Ee + h * HD + lm) * Nn + quad * 4;

#pragma unroll 1
  for (int kt = 0; kt <= qt; ++kt) {
    const int k0 = kt * 64;

    // K A-frags: A[key=f*16+lm][e=quad*8+j+ks*32], direct from global
    bf16x8 kf[4][2];
#pragma unroll
    for (int f = 0; f < 4; ++f) {
      const bf16* kp = kr + (size_t)(k0 + f * 16) * Ee;
      kf[f][0] = *(const bf16x8*)kp;
      kf[f][1] = *(const bf16x8*)(kp + 32);
    }
    // V^T A-frags (16x16x16): A[d=df*16+lm][key=k0+c*16+quad*4+j]
    bf16x4 vf[4][4];
#pragma unroll
    for (int df = 0; df < 4; ++df) {
      const bf16* vp = vr + (size_t)(df * 16) * Nn + k0;
#pragma unroll
      for (int c = 0; c < 4; ++c) vf[df][c] = *(const bf16x4*)(vp + c * 16);
    }

    // S^T = K Q^T
    floatx4 accS[4];
#pragma unroll
    for (int f = 0; f < 4; ++f) accS[f] = (floatx4){0.f, 0.f, 0.f, 0.f};
#pragma unroll
    for (int ks = 0; ks < 2; ++ks)
#pragma unroll
      for (int f = 0; f < 4; ++f)
        accS[f] = __builtin_amdgcn_mfma_f32_16x16x32_bf16(
            kf[f][ks], qf[ks], accS[f], 0, 0, 0);

    // softmax + pack: value (f, r) is key = k0+f*16+quad*4+r, col q = qglob
    const bool diag = (kt == qt);
    short4v pb[4];
#pragma unroll
    for (int f = 0; f < 4; ++f) {
      union { bf16 h4[4]; short4v s; } u;
#pragma unroll
      for (int r = 0; r < 4; ++r) {
        float pv = __builtin_exp2f(accS[f][r] - SHIFT);
        if (diag && (k0 + f * 16 + quad * 4 + r) > qglob) pv = 0.f;
        bf16 pbv = (bf16)pv;
        lsum += (float)pbv;  // sum the rounded values PV will actually use
        u.h4[r] = pbv;
      }
      pb[f] = u.s;
    }

    // O^T += V^T P^T (key chunks of 16)
#pragma unroll
    for (int c = 0; c < 4; ++c) {
#pragma unroll
      for (int df = 0; df < 4; ++df) {
        union { bf16x4 b; short4v s; } cv;
        cv.b = vf[df][c];
        accO[df] = __builtin_amdgcn_mfma_f32_16x16x16bf16_1k(
            cv.s, pb[c], accO[df], 0, 0, 0);
      }
    }
  }

  // l for column q lives split across the 4 quads (lanes lm+16k)
  lsum += __shfl_xor(lsum, 16);
  lsum += __shfl_xor(lsum, 32);
  const float inv = 1.0f / lsum;

  // epilogue: accO[df] rows d = df*16+quad*4+r, col q = qglob
#pragma unroll
  for (int df = 0; df < 4; ++df) {
#pragma unroll
    for (int r = 0; r < 4; ++r) {
      int d = h * HD + df * 16 + quad * 4 + r;
      size_t off = ((size_t)b * Ee + d) * Nn + qglob;
      if (!f32) ((bf16*)Out)[off] = (bf16)(accO[df][r] * inv);
      else      ((float*)Out)[off] = accO[df][r] * inv;
    }
  }
}

// ---------------------------------------------------------------- launch
extern "C" void kernel_launch(void* const* d_in, const int* in_sizes, int n_in,
                              void* d_out, int out_size, void* d_ws,
                              size_t ws_size, hipStream_t stream) {
  const void* q  = d_in[0];
  const void* k  = d_in[1];
  const void* Wq = d_in[2];
  const void* bq = d_in[3];
  const void* Wk = d_in[4];
  const void* bk = d_in[5];
  const void* Wv = d_in[6];
  const void* bv = d_in[7];

  const size_t SZ = (size_t)B_ * Nn * Cc;  // 4M elems = 8MB bf16 per region
  // ws: [flag 1KB][Xtq 8MB][Qt 8MB][Kt 8MB].
  // d_out (16MB when fp32): lower 8MB = Xtk scratch, upper 8MB = bf16 W/bias
  // copies (only written when flag=1, i.e. when the buffer is 16MB).
  int*  flag = (int*)d_ws;
  bf16* Xtq  = (bf16*)((char*)d_ws + 1024);
  bf16* Qt   = Xtq + SZ;
  bf16* Kt   = Qt + SZ;
  bf16* Xtk  = (bf16*)d_out;                          // dead before attn writes
  bf16* Vh   = Xtq;                                   // V e-major (B,E,N)
  bf16* Wb   = (bf16*)((char*)d_out + 8 * 1024 * 1024);
  bf16* Wqb = Wb,            *Wkb = Wb + WSEG,        *Wvb = Wb + 2 * WSEG;
  bf16* bqb = Wb + 3 * WSEG, *bkb = bqb + 512,        *bvb = bqb + 1024;

  detect_dtype<<<1, 64, 0, stream>>>((const unsigned short*)Wq, flag);
  wcvt<<<(WTOT / 8 + 255) / 256, 256, 0, stream>>>(
      (const float*)Wq, (const float*)Wk, (const float*)Wv,
      (const float*)bq, (const float*)bk, (const float*)bv, Wb, flag);
  transpose_k<<<dim3(64, 8, 4), 256, 0, stream>>>(q, k, Xtq, Xtk, flag);
  gemm_bt<<<dim3(32, 8, 2), 256, 0, stream>>>(
      Xtq, Xtq, (long)Nn * Cc, Wq, Wqb, 0L, bq, bqb,
      Qt, (long)Nn * Ee, Ee, 0, QSCALE, flag);
  gemm_bt<<<dim3(32, 8, 2), 256, 0, stream>>>(
      Xtk, Xtk, (long)Nn * Cc, Wk, Wkb, 0L, bk, bkb,
      Kt, (long)Nn * Ee, Ee, 0, 1.0f, flag);
  gemm_bt<<<dim3(4, 64, 2), 256, 0, stream>>>(
      Wv, Wvb, 0L, Xtk, Xtk, (long)Nn * Cc, bv, bvb,
      Vh, (long)Ee * Nn, Nn, 1, 1.0f, flag);
  attn<<<dim3(64, NH, B_), 256, 0, stream>>>(Qt, Kt, Vh, d_out, flag);
}

// Round 6
// 283.765 us; speedup vs baseline: 2.8283x; 2.8283x over previous
//
#include <hip/hip_runtime.h>

// CausalAttention2d: B=2, C=512, H=W=64 (N=4096 tokens), E=512, nh=8, hd=64.
// Inputs fp32 (runtime-detected; bf16 path kept defensively). Pipeline:
//   detect -> wcvt (W,b -> bf16) -> transpose -> gemm x3 -> flash attn.
// Round 6 attn = hybrid of r4/r5: coalesced LDS staging for K,V (r4) +
// register-resident P via S^T = K*Q^T (r5; P^T lands in the exact B-frag of
// mfma_16x16x16bf16_1k). No Ps LDS, no scalar ds_write_b16 (r4's 9.6M
// conflict cycles), no uncoalesced global (r5's L1 meltdown).

typedef __bf16 bf16;
typedef __attribute__((ext_vector_type(8))) __bf16 bf16x8;
typedef __attribute__((ext_vector_type(4))) __bf16 bf16x4;
typedef __attribute__((ext_vector_type(4))) short short4v;
typedef __attribute__((ext_vector_type(4))) float floatx4;

#define B_ 2
#define Cc 512
#define Nn 4096
#define Ee 512
#define NH 8
#define HD 64

#define QSCALE 0.1803368801111204f   // log2(e)/8, folded into Q
#define SHIFT 11.541560327111707f    // 8*log2(e): p = 2^(s - SHIFT)

// ---------------------------------------------------------------- detector
// One wave. flag=1 -> inputs are fp32; flag=0 -> inputs are bf16.
__global__ __launch_bounds__(64) void detect_dtype(
    const unsigned short* __restrict__ w, int* __restrict__ flag) {
  bool bad = false;
#pragma unroll
  for (int i = 0; i < 16; ++i) {
    unsigned u = w[threadIdx.x * 16 + i];
    float v = __uint_as_float(u << 16);
    bad |= !(v > -1024.f && v < 1024.f);  // catches big / inf / NaN
  }
  unsigned long long b = __ballot(bad);
  if (threadIdx.x == 0) *flag = (b != 0ull) ? 1 : 0;
}

// ---------------------------------------------------------------- wcvt
// fp32 -> bf16 conversion of Wq,Wk,Wv,bq,bk,bv into one packed region.
// Only runs when flag=1 (region lives in d_out's upper half, fp32-only).
#define WSEG 262144          // 512*512
#define WTOT 787968          // 3*WSEG + 3*512
__global__ __launch_bounds__(256) void wcvt(
    const float* __restrict__ Wq, const float* __restrict__ Wk,
    const float* __restrict__ Wv, const float* __restrict__ bq,
    const float* __restrict__ bk, const float* __restrict__ bv,
    bf16* __restrict__ out, const int* __restrict__ flagp) {
  if (!*flagp) return;
  int idx = (blockIdx.x * 256 + threadIdx.x) * 8;
  if (idx >= WTOT) return;
  const float* src;
  int off;
  if (idx < WSEG)            { src = Wq; off = idx; }
  else if (idx < 2 * WSEG)   { src = Wk; off = idx - WSEG; }
  else if (idx < 3 * WSEG)   { src = Wv; off = idx - 2 * WSEG; }
  else if (idx < 3 * WSEG + 512)  { src = bq; off = idx - 3 * WSEG; }
  else if (idx < 3 * WSEG + 1024) { src = bk; off = idx - 3 * WSEG - 512; }
  else                            { src = bv; off = idx - 3 * WSEG - 1024; }
  float4 a = *(const float4*)(src + off);
  float4 c = *(const float4*)(src + off + 4);
  union { bf16 h[8]; bf16x8 v; } u;
  u.h[0] = (bf16)a.x; u.h[1] = (bf16)a.y; u.h[2] = (bf16)a.z; u.h[3] = (bf16)a.w;
  u.h[4] = (bf16)c.x; u.h[5] = (bf16)c.y; u.h[6] = (bf16)c.z; u.h[7] = (bf16)c.w;
  *(bf16x8*)(out + idx) = u.v;
}

// load 8 consecutive elements as bf16x8 from bf16 (f32=0) or fp32 (f32=1).
__device__ __forceinline__ bf16x8 load8e(const void* base, size_t eidx, int f32) {
  if (!f32) return *(const bf16x8*)((const bf16*)base + eidx);
  const float* f = (const float*)base + eidx;
  float4 a = *(const float4*)f;
  float4 c = *(const float4*)(f + 4);
  union { bf16 h[8]; bf16x8 v; } u;
  u.h[0] = (bf16)a.x; u.h[1] = (bf16)a.y; u.h[2] = (bf16)a.z; u.h[3] = (bf16)a.w;
  u.h[4] = (bf16)c.x; u.h[5] = (bf16)c.y; u.h[6] = (bf16)c.z; u.h[7] = (bf16)c.w;
  return u.v;
}

// ---------------------------------------------------------------- transpose
// (B,C,N) -> (B,N,C) for query and key; output always bf16 token-major.
__global__ __launch_bounds__(256) void transpose_k(
    const void* __restrict__ X0, const void* __restrict__ X1,
    bf16* __restrict__ T0, bf16* __restrict__ T1,
    const int* __restrict__ flagp) {
  const int f32 = *flagp;
  __shared__ __align__(16) bf16 T[64 * 64];
  const int z = blockIdx.z;
  const int bb = z & 1;
  const void* src = (z >> 1) ? X1 : X0;
  bf16* dst = (z >> 1) ? T1 : T0;
  const int n0 = blockIdx.x * 64, c0 = blockIdx.y * 64;
  const int t = threadIdx.x;
  const size_t sbase = ((size_t)bb * Cc + c0) * (size_t)Nn + n0;

#pragma unroll
  for (int it = 0; it < 2; ++it) {
    int task = t + it * 256;            // 512 tasks: 64 c-rows x 8 n-granules
    int crow = task >> 3, gr = task & 7;
    bf16x8 v = load8e(src, sbase + (size_t)crow * Nn + gr * 8, f32);
    int slot = gr ^ (crow & 7);
    *(bf16x8*)&T[crow * 64 + slot * 8] = v;
  }
  __syncthreads();
  const int nrow = t & 63, cp = t >> 6;
  bf16* db = dst + ((size_t)bb * Nn + n0 + nrow) * Cc + c0;
#pragma unroll
  for (int it = 0; it < 2; ++it) {
    int cg = cp * 2 + it;               // c-granule 0..7
    union { bf16 h[8]; bf16x8 v; } u;
#pragma unroll
    for (int j = 0; j < 8; ++j) {
      int c = cg * 8 + j;
      int slot = (nrow >> 3) ^ (c & 7);
      u.h[j] = T[c * 64 + slot * 8 + (nrow & 7)];
    }
    *(bf16x8*)(db + cg * 8) = u.v;
  }
}

// ---------------------------------------------------------------- gemm_bt
// Out[m][n] = (sum_k A[m][k]*Bt[n][k] + bias) * scaleOut.
// Operand pointers: (P0, P1) -> use P1 when flag=1 (bf16-converted W),
// P0 when flag=0 (original bf16). ws operands pass the same ptr twice.
// Tile 128(m) x 64(n) x BK=32, 4 waves, 16x16x32 bf16 MFMA, stride-40 LDS.
__global__ __launch_bounds__(256) void gemm_bt(
    const void* __restrict__ A0, const bf16* __restrict__ A1, long sAb,
    const void* __restrict__ B0, const bf16* __restrict__ B1, long sBb,
    const void* __restrict__ bias0, const bf16* __restrict__ bias1,
    bf16* __restrict__ Out, long sOb,
    int Nq, int biasOnM, float scaleOut, const int* __restrict__ flagp) {
  const int f32 = *flagp;
  const bf16* A = f32 ? A1 : (const bf16*)A0;
  const bf16* Bt = f32 ? B1 : (const bf16*)B0;
  const bf16* bias = f32 ? bias1 : (const bf16*)bias0;
  constexpr int K = 512;
  constexpr int SA = 40;  // padded stride (80B, 16B-aligned)
  __shared__ __align__(16) bf16 As[128 * SA];
  __shared__ __align__(16) bf16 Bs[64 * SA];
  const int tid = threadIdx.x;
  const int lane = tid & 63, wave = tid >> 6;
  const int quad = lane >> 4, lm = lane & 15;
  const int m0 = blockIdx.x * 128, n0 = blockIdx.y * 64;
  const int b = blockIdx.z;
  const bf16* Ab = A + (size_t)b * sAb;
  const bf16* Bb = Bt + (size_t)b * sBb;
  bf16* Ob = Out + (size_t)b * sOb;

  const int arow = tid >> 2, ag = tid & 3;  // staging task split

  floatx4 acc[2][4];
#pragma unroll
  for (int i = 0; i < 2; ++i)
#pragma unroll
    for (int j = 0; j < 4; ++j) acc[i][j] = (floatx4){0.f, 0.f, 0.f, 0.f};

  for (int k0 = 0; k0 < K; k0 += 32) {
    bf16x8 a0 = *(const bf16x8*)(Ab + (size_t)(m0 + arow) * K + k0 + ag * 8);
    bf16x8 a1 = *(const bf16x8*)(Ab + (size_t)(m0 + 64 + arow) * K + k0 + ag * 8);
    bf16x8 b0 = *(const bf16x8*)(Bb + (size_t)(n0 + arow) * K + k0 + ag * 8);
    __syncthreads();  // previous iteration's LDS reads complete
    *(bf16x8*)&As[arow * SA + ag * 8] = a0;
    *(bf16x8*)&As[(64 + arow) * SA + ag * 8] = a1;
    *(bf16x8*)&Bs[arow * SA + ag * 8] = b0;
    __syncthreads();  // staging complete

    bf16x8 af[2], bfr[4];
#pragma unroll
    for (int mf = 0; mf < 2; ++mf) {
      int r = wave * 32 + mf * 16 + lm;
      af[mf] = *(const bf16x8*)&As[r * SA + quad * 8];
    }
#pragma unroll
    for (int nf = 0; nf < 4; ++nf) {
      int r = nf * 16 + lm;
      bfr[nf] = *(const bf16x8*)&Bs[r * SA + quad * 8];
    }
#pragma unroll
    for (int mf = 0; mf < 2; ++mf)
#pragma unroll
      for (int nf = 0; nf < 4; ++nf)
        acc[mf][nf] = __builtin_amdgcn_mfma_f32_16x16x32_bf16(
            af[mf], bfr[nf], acc[mf][nf], 0, 0, 0);
  }

  // epilogue: C layout col=lane&15, row=quad*4+reg
#pragma unroll
  for (int mf = 0; mf < 2; ++mf) {
#pragma unroll
    for (int nf = 0; nf < 4; ++nf) {
      int col = n0 + nf * 16 + lm;
      float bn = biasOnM ? 0.f : (float)bias[col];
#pragma unroll
      for (int r = 0; r < 4; ++r) {
        int rowg = m0 + wave * 32 + mf * 16 + quad * 4 + r;
        float bv = biasOnM ? (float)bias[rowg] : bn;
        Ob[(size_t)rowg * Nq + col] = (bf16)((acc[mf][nf][r] + bv) * scaleOut);
      }
    }
  }
}

// ---------------------------------------------------------------- attention
// Per (b, head): 1024 blocks x 256 thr; wave w owns 16 q-columns (lm).
// Per 64-key tile:
//   stage K[key][e] and V^T[d][key] into LDS (coalesced global b128 loads)
//   S^T[key][q] = K*Q^T: A = K from LDS ds_read_b128, B = Q persistent regs
//   p = 2^(s-SHIFT) (+causal), packed in-lane -> exact B-frag of
//   mfma_16x16x16bf16_1k (P never touches LDS)
//   O^T[d][q] += V^T*P^T: A = V^T from LDS ds_read_b64
// Epilogue: O^T C-layout -> all regs share col q -> single 1/l per lane.
__global__ __launch_bounds__(256, 4) void attn(
    const bf16* __restrict__ Qt, const bf16* __restrict__ Kt,
    const bf16* __restrict__ Ve, void* __restrict__ Out,
    const int* __restrict__ flagp) {
  const int f32 = *flagp;
  constexpr int SK = 72;  // padded stride (144B, 16B-aligned)
  __shared__ __align__(16) bf16 Ks[64 * SK];   // Ks[key][e]
  __shared__ __align__(16) bf16 Vs[64 * SK];   // Vs[d][key]
  const int tid = threadIdx.x, lane = tid & 63, w = tid >> 6;
  const int quad = lane >> 4, lm = lane & 15;
  const int qt = 63 - (int)blockIdx.x;  // heavy tiles dispatch first
  const int h = blockIdx.y, b = blockIdx.z;
  const int n0 = qt * 64;
  const int qglob = n0 + w * 16 + lm;

  // Q B-frag (persistent): B[e=quad*8+j (+32*ks)][q=lm]
  bf16x8 qf[2];
  {
    const bf16* qp = Qt + ((size_t)b * Nn + qglob) * Ee + h * HD + quad * 8;
    qf[0] = *(const bf16x8*)qp;
    qf[1] = *(const bf16x8*)(qp + 32);
  }
  floatx4 accO[4];
#pragma unroll
  for (int df = 0; df < 4; ++df) accO[df] = (floatx4){0.f, 0.f, 0.f, 0.f};
  float lsum = 0.f;

  // staging: r0 = tid>>3 in [0,32), g = tid&7; rows r0 and r0+32
  const int r0 = tid >> 3, g = tid & 7;
  const bf16* kp0 = Kt + ((size_t)b * Nn + r0) * Ee + h * HD + g * 8;
  const bf16* kp1 = kp0 + (size_t)32 * Ee;
  const bf16* vp0 = Ve + ((size_t)b * Ee + h * HD + r0) * Nn + g * 8;
  const bf16* vp1 = vp0 + (size_t)32 * Nn;

#pragma unroll 1
  for (int kt = 0; kt <= qt; ++kt) {
    const int k0 = kt * 64;
    bf16x8 ka = *(const bf16x8*)kp0;
    bf16x8 kb = *(const bf16x8*)kp1;
    bf16x8 va = *(const bf16x8*)vp0;
    bf16x8 vb = *(const bf16x8*)vp1;
    kp0 += (size_t)64 * Ee; kp1 += (size_t)64 * Ee;
    vp0 += 64; vp1 += 64;
    __syncthreads();  // prior iteration's Ks/Vs reads complete
    *(bf16x8*)&Ks[r0 * SK + g * 8] = ka;
    *(bf16x8*)&Ks[(r0 + 32) * SK + g * 8] = kb;
    *(bf16x8*)&Vs[r0 * SK + g * 8] = va;
    *(bf16x8*)&Vs[(r0 + 32) * SK + g * 8] = vb;
    __syncthreads();  // staging complete

    // S^T = K Q^T : A[key=f*16+lm][e=quad*8+j+ks*32] from Ks
    floatx4 accS[4];
#pragma unroll
    for (int f = 0; f < 4; ++f) accS[f] = (floatx4){0.f, 0.f, 0.f, 0.f};
#pragma unroll
    for (int ks = 0; ks < 2; ++ks)
#pragma unroll
      for (int f = 0; f < 4; ++f) {
        bf16x8 ak = *(const bf16x8*)&Ks[(f * 16 + lm) * SK + ks * 32 + quad * 8];
        accS[f] = __builtin_amdgcn_mfma_f32_16x16x32_bf16(
            ak, qf[ks], accS[f], 0, 0, 0);
      }

    // softmax + pack: value (f, r) is key = k0+f*16+quad*4+r, col q = qglob
    const bool diag = (kt == qt);
    short4v pb[4];
#pragma unroll
    for (int f = 0; f < 4; ++f) {
      union { bf16 h4[4]; short4v s; } u;
#pragma unroll
      for (int r = 0; r < 4; ++r) {
        float pv = __builtin_exp2f(accS[f][r] - SHIFT);
        if (diag && (k0 + f * 16 + quad * 4 + r) > qglob) pv = 0.f;
        bf16 pbv = (bf16)pv;
        lsum += (float)pbv;  // sum the rounded values PV will actually use
        u.h4[r] = pbv;
      }
      pb[f] = u.s;
    }

    // O^T += V^T P^T : A[d=df*16+lm][key=c*16+quad*4+j] from Vs (b64)
#pragma unroll
    for (int c = 0; c < 4; ++c) {
#pragma unroll
      for (int df = 0; df < 4; ++df) {
        union { bf16x4 b; short4v s; } cv;
        cv.b = *(const bf16x4*)&Vs[(df * 16 + lm) * SK + c * 16 + quad * 4];
        accO[df] = __builtin_amdgcn_mfma_f32_16x16x16bf16_1k(
            cv.s, pb[c], accO[df], 0, 0, 0);
      }
    }
  }

  // l for column q lives split across the 4 quads (lanes lm+16k)
  lsum += __shfl_xor(lsum, 16);
  lsum += __shfl_xor(lsum, 32);
  const float inv = 1.0f / lsum;

  // epilogue: accO[df] rows d = df*16+quad*4+r, col q = qglob
#pragma unroll
  for (int df = 0; df < 4; ++df) {
#pragma unroll
    for (int r = 0; r < 4; ++r) {
      int d = h * HD + df * 16 + quad * 4 + r;
      size_t off = ((size_t)b * Ee + d) * Nn + qglob;
      if (!f32) ((bf16*)Out)[off] = (bf16)(accO[df][r] * inv);
      else      ((float*)Out)[off] = accO[df][r] * inv;
    }
  }
}

// ---------------------------------------------------------------- launch
extern "C" void kernel_launch(void* const* d_in, const int* in_sizes, int n_in,
                              void* d_out, int out_size, void* d_ws,
                              size_t ws_size, hipStream_t stream) {
  const void* q  = d_in[0];
  const void* k  = d_in[1];
  const void* Wq = d_in[2];
  const void* bq = d_in[3];
  const void* Wk = d_in[4];
  const void* bk = d_in[5];
  const void* Wv = d_in[6];
  const void* bv = d_in[7];

  const size_t SZ = (size_t)B_ * Nn * Cc;  // 4M elems = 8MB bf16 per region
  // ws: [flag 1KB][Xtq 8MB][Qt 8MB][Kt 8MB].
  // d_out (16MB when fp32): lower 8MB = Xtk scratch, upper 8MB = bf16 W/bias
  // copies (only written when flag=1, i.e. when the buffer is 16MB).
  int*  flag = (int*)d_ws;
  bf16* Xtq  = (bf16*)((char*)d_ws + 1024);
  bf16* Qt   = Xtq + SZ;
  bf16* Kt   = Qt + SZ;
  bf16* Xtk  = (bf16*)d_out;                          // dead before attn writes
  bf16* Vh   = Xtq;                                   // V e-major (B,E,N)
  bf16* Wb   = (bf16*)((char*)d_out + 8 * 1024 * 1024);
  bf16* Wqb = Wb,            *Wkb = Wb + WSEG,        *Wvb = Wb + 2 * WSEG;
  bf16* bqb = Wb + 3 * WSEG, *bkb = bqb + 512,        *bvb = bqb + 1024;

  detect_dtype<<<1, 64, 0, stream>>>((const unsigned short*)Wq, flag);
  wcvt<<<(WTOT / 8 + 255) / 256, 256, 0, stream>>>(
      (const float*)Wq, (const float*)Wk, (const float*)Wv,
      (const float*)bq, (const float*)bk, (const float*)bv, Wb, flag);
  transpose_k<<<dim3(64, 8, 4), 256, 0, stream>>>(q, k, Xtq, Xtk, flag);
  gemm_bt<<<dim3(32, 8, 2), 256, 0, stream>>>(
      Xtq, Xtq, (long)Nn * Cc, Wq, Wqb, 0L, bq, bqb,
      Qt, (long)Nn * Ee, Ee, 0, QSCALE, flag);
  gemm_bt<<<dim3(32, 8, 2), 256, 0, stream>>>(
      Xtk, Xtk, (long)Nn * Cc, Wk, Wkb, 0L, bk, bkb,
      Kt, (long)Nn * Ee, Ee, 0, 1.0f, flag);
  gemm_bt<<<dim3(4, 64, 2), 256, 0, stream>>>(
      Wv, Wvb, 0L, Xtk, Xtk, (long)Nn * Cc, bv, bvb,
      Vh, (long)Ee * Nn, Nn, 1, 1.0f, flag);
  attn<<<dim3(64, NH, B_), 256, 0, stream>>>(Qt, Kt, Vh, d_out, flag);
}

// Round 7
// 261.672 us; speedup vs baseline: 3.0671x; 1.0844x over previous
//
#include <hip/hip_runtime.h>

// CausalAttention2d: B=2, C=512, H=W=64 (N=4096 tokens), E=512, nh=8, hd=64.
// Inputs fp32 (runtime-detected; bf16 path kept defensively). Pipeline:
//   detect -> wcvt (W,b -> bf16) -> transpose -> gemm x3 -> flash attn.
// Round 7: attn = 32 q/wave (2 Q-frags share every K/V LDS read), 128 q/block,
// double-buffered LDS with register prefetch and ONE barrier per k-tile;
// z-complement block pairing (p_eff = bz ? 31-bx : bx) makes each CU's
// co-resident pair a uniform 68 key-tiles. gemm_bt gets the same dbuf
// one-barrier pipeline. Register-resident P (r5/r6 verified layouts).

typedef __bf16 bf16;
typedef __attribute__((ext_vector_type(8))) __bf16 bf16x8;
typedef __attribute__((ext_vector_type(4))) __bf16 bf16x4;
typedef __attribute__((ext_vector_type(4))) short short4v;
typedef __attribute__((ext_vector_type(4))) float floatx4;

#define B_ 2
#define Cc 512
#define Nn 4096
#define Ee 512
#define NH 8
#define HD 64

#define QSCALE 0.1803368801111204f   // log2(e)/8, folded into Q
#define SHIFT 11.541560327111707f    // 8*log2(e): p = 2^(s - SHIFT)

// ---------------------------------------------------------------- detector
__global__ __launch_bounds__(64) void detect_dtype(
    const unsigned short* __restrict__ w, int* __restrict__ flag) {
  bool bad = false;
#pragma unroll
  for (int i = 0; i < 16; ++i) {
    unsigned u = w[threadIdx.x * 16 + i];
    float v = __uint_as_float(u << 16);
    bad |= !(v > -1024.f && v < 1024.f);  // catches big / inf / NaN
  }
  unsigned long long b = __ballot(bad);
  if (threadIdx.x == 0) *flag = (b != 0ull) ? 1 : 0;
}

// ---------------------------------------------------------------- wcvt
#define WSEG 262144          // 512*512
#define WTOT 787968          // 3*WSEG + 3*512
__global__ __launch_bounds__(256) void wcvt(
    const float* __restrict__ Wq, const float* __restrict__ Wk,
    const float* __restrict__ Wv, const float* __restrict__ bq,
    const float* __restrict__ bk, const float* __restrict__ bv,
    bf16* __restrict__ out, const int* __restrict__ flagp) {
  if (!*flagp) return;
  int idx = (blockIdx.x * 256 + threadIdx.x) * 8;
  if (idx >= WTOT) return;
  const float* src;
  int off;
  if (idx < WSEG)            { src = Wq; off = idx; }
  else if (idx < 2 * WSEG)   { src = Wk; off = idx - WSEG; }
  else if (idx < 3 * WSEG)   { src = Wv; off = idx - 2 * WSEG; }
  else if (idx < 3 * WSEG + 512)  { src = bq; off = idx - 3 * WSEG; }
  else if (idx < 3 * WSEG + 1024) { src = bk; off = idx - 3 * WSEG - 512; }
  else                            { src = bv; off = idx - 3 * WSEG - 1024; }
  float4 a = *(const float4*)(src + off);
  float4 c = *(const float4*)(src + off + 4);
  union { bf16 h[8]; bf16x8 v; } u;
  u.h[0] = (bf16)a.x; u.h[1] = (bf16)a.y; u.h[2] = (bf16)a.z; u.h[3] = (bf16)a.w;
  u.h[4] = (bf16)c.x; u.h[5] = (bf16)c.y; u.h[6] = (bf16)c.z; u.h[7] = (bf16)c.w;
  *(bf16x8*)(out + idx) = u.v;
}

// load 8 consecutive elements as bf16x8 from bf16 (f32=0) or fp32 (f32=1).
__device__ __forceinline__ bf16x8 load8e(const void* base, size_t eidx, int f32) {
  if (!f32) return *(const bf16x8*)((const bf16*)base + eidx);
  const float* f = (const float*)base + eidx;
  float4 a = *(const float4*)f;
  float4 c = *(const float4*)(f + 4);
  union { bf16 h[8]; bf16x8 v; } u;
  u.h[0] = (bf16)a.x; u.h[1] = (bf16)a.y; u.h[2] = (bf16)a.z; u.h[3] = (bf16)a.w;
  u.h[4] = (bf16)c.x; u.h[5] = (bf16)c.y; u.h[6] = (bf16)c.z; u.h[7] = (bf16)c.w;
  return u.v;
}

// ---------------------------------------------------------------- transpose
// (B,C,N) -> (B,N,C) for query and key; output always bf16 token-major.
__global__ __launch_bounds__(256) void transpose_k(
    const void* __restrict__ X0, const void* __restrict__ X1,
    bf16* __restrict__ T0, bf16* __restrict__ T1,
    const int* __restrict__ flagp) {
  const int f32 = *flagp;
  __shared__ __align__(16) bf16 T[64 * 64];
  const int z = blockIdx.z;
  const int bb = z & 1;
  const void* src = (z >> 1) ? X1 : X0;
  bf16* dst = (z >> 1) ? T1 : T0;
  const int n0 = blockIdx.x * 64, c0 = blockIdx.y * 64;
  const int t = threadIdx.x;
  const size_t sbase = ((size_t)bb * Cc + c0) * (size_t)Nn + n0;

#pragma unroll
  for (int it = 0; it < 2; ++it) {
    int task = t + it * 256;            // 512 tasks: 64 c-rows x 8 n-granules
    int crow = task >> 3, gr = task & 7;
    bf16x8 v = load8e(src, sbase + (size_t)crow * Nn + gr * 8, f32);
    int slot = gr ^ (crow & 7);
    *(bf16x8*)&T[crow * 64 + slot * 8] = v;
  }
  __syncthreads();
  const int nrow = t & 63, cp = t >> 6;
  bf16* db = dst + ((size_t)bb * Nn + n0 + nrow) * Cc + c0;
#pragma unroll
  for (int it = 0; it < 2; ++it) {
    int cg = cp * 2 + it;               // c-granule 0..7
    union { bf16 h[8]; bf16x8 v; } u;
#pragma unroll
    for (int j = 0; j < 8; ++j) {
      int c = cg * 8 + j;
      int slot = (nrow >> 3) ^ (c & 7);
      u.h[j] = T[c * 64 + slot * 8 + (nrow & 7)];
    }
    *(bf16x8*)(db + cg * 8) = u.v;
  }
}

// ---------------------------------------------------------------- gemm_bt
// Out[m][n] = (sum_k A[m][k]*Bt[n][k] + bias) * scaleOut.
// Double-buffered LDS, one barrier per K-step, register prefetch.
__global__ __launch_bounds__(256) void gemm_bt(
    const void* __restrict__ A0, const bf16* __restrict__ A1, long sAb,
    const void* __restrict__ B0, const bf16* __restrict__ B1, long sBb,
    const void* __restrict__ bias0, const bf16* __restrict__ bias1,
    bf16* __restrict__ Out, long sOb,
    int Nq, int biasOnM, float scaleOut, const int* __restrict__ flagp) {
  const int f32 = *flagp;
  const bf16* A = f32 ? A1 : (const bf16*)A0;
  const bf16* Bt = f32 ? B1 : (const bf16*)B0;
  const bf16* bias = f32 ? bias1 : (const bf16*)bias0;
  constexpr int K = 512;
  constexpr int SA = 40;  // padded stride (80B, 16B-aligned)
  __shared__ __align__(16) bf16 As[2][128 * SA];
  __shared__ __align__(16) bf16 Bs[2][64 * SA];
  const int tid = threadIdx.x;
  const int lane = tid & 63, wave = tid >> 6;
  const int quad = lane >> 4, lm = lane & 15;
  const int m0 = blockIdx.x * 128, n0 = blockIdx.y * 64;
  const int b = blockIdx.z;
  const bf16* Ab = A + (size_t)b * sAb;
  const bf16* Bb = Bt + (size_t)b * sBb;
  bf16* Ob = Out + (size_t)b * sOb;

  const int arow = tid >> 2, ag = tid & 3;  // staging task split

  floatx4 acc[2][4];
#pragma unroll
  for (int i = 0; i < 2; ++i)
#pragma unroll
    for (int j = 0; j < 4; ++j) acc[i][j] = (floatx4){0.f, 0.f, 0.f, 0.f};

  // prologue: tile 0 into buf 0
  bf16x8 a0 = *(const bf16x8*)(Ab + (size_t)(m0 + arow) * K + ag * 8);
  bf16x8 a1 = *(const bf16x8*)(Ab + (size_t)(m0 + 64 + arow) * K + ag * 8);
  bf16x8 b0 = *(const bf16x8*)(Bb + (size_t)(n0 + arow) * K + ag * 8);
  *(bf16x8*)&As[0][arow * SA + ag * 8] = a0;
  *(bf16x8*)&As[0][(64 + arow) * SA + ag * 8] = a1;
  *(bf16x8*)&Bs[0][arow * SA + ag * 8] = b0;
  __syncthreads();

  for (int kk = 0; kk < 16; ++kk) {
    const int c = kk & 1;
    const bool more = kk < 15;
    if (more) {
      int k0 = (kk + 1) * 32;
      a0 = *(const bf16x8*)(Ab + (size_t)(m0 + arow) * K + k0 + ag * 8);
      a1 = *(const bf16x8*)(Ab + (size_t)(m0 + 64 + arow) * K + k0 + ag * 8);
      b0 = *(const bf16x8*)(Bb + (size_t)(n0 + arow) * K + k0 + ag * 8);
    }
    bf16x8 af[2], bfr[4];
#pragma unroll
    for (int mf = 0; mf < 2; ++mf) {
      int r = wave * 32 + mf * 16 + lm;
      af[mf] = *(const bf16x8*)&As[c][r * SA + quad * 8];
    }
#pragma unroll
    for (int nf = 0; nf < 4; ++nf) {
      int r = nf * 16 + lm;
      bfr[nf] = *(const bf16x8*)&Bs[c][r * SA + quad * 8];
    }
    if (more) {
      *(bf16x8*)&As[c ^ 1][arow * SA + ag * 8] = a0;
      *(bf16x8*)&As[c ^ 1][(64 + arow) * SA + ag * 8] = a1;
      *(bf16x8*)&Bs[c ^ 1][arow * SA + ag * 8] = b0;
    }
#pragma unroll
    for (int mf = 0; mf < 2; ++mf)
#pragma unroll
      for (int nf = 0; nf < 4; ++nf)
        acc[mf][nf] = __builtin_amdgcn_mfma_f32_16x16x32_bf16(
            af[mf], bfr[nf], acc[mf][nf], 0, 0, 0);
    __syncthreads();
  }

  // epilogue: C layout col=lane&15, row=quad*4+reg
#pragma unroll
  for (int mf = 0; mf < 2; ++mf) {
#pragma unroll
    for (int nf = 0; nf < 4; ++nf) {
      int col = n0 + nf * 16 + lm;
      float bn = biasOnM ? 0.f : (float)bias[col];
#pragma unroll
      for (int r = 0; r < 4; ++r) {
        int rowg = m0 + wave * 32 + mf * 16 + quad * 4 + r;
        float bv = biasOnM ? (float)bias[rowg] : bn;
        Ob[(size_t)rowg * Nq + col] = (bf16)((acc[mf][nf][r] + bv) * scaleOut);
      }
    }
  }
}

// ---------------------------------------------------------------- attention
// Block = 4 waves x 32 q = 128 q-rows; wave w owns q [Q0+w*32, +32) via two
// 16-q B-frags that SHARE every K/V LDS read. Double-buffered Ks/Vs, register
// prefetch, one barrier per 64-key tile. p_eff = bz ? 31-bx : bx so the
// co-resident block pair per CU totals a uniform 68 tiles.
__global__ __launch_bounds__(256, 2) void attn(
    const bf16* __restrict__ Qt, const bf16* __restrict__ Kt,
    const bf16* __restrict__ Ve, void* __restrict__ Out,
    const int* __restrict__ flagp) {
  const int f32 = *flagp;
  constexpr int SK = 72;  // padded stride (144B, 16B-aligned)
  __shared__ __align__(16) bf16 Ks[2][64 * SK];   // [buf][key][e]
  __shared__ __align__(16) bf16 Vs[2][64 * SK];   // [buf][d][key]
  const int tid = threadIdx.x, lane = tid & 63, w = tid >> 6;
  const int quad = lane >> 4, lm = lane & 15;
  const int b = blockIdx.z, h = blockIdx.y;
  const int p = b ? (31 - (int)blockIdx.x) : (int)blockIdx.x;
  const int Q0 = p * 128;
  const int qbase = Q0 + w * 32;        // wave's first q-row
  const int last = 2 * p + 1;           // last 64-key tile index

  // Q B-frags (persistent): qf[qi][ks] = B[e=quad*8+j+ks*32][q=qi*16+lm]
  bf16x8 qf[2][2];
#pragma unroll
  for (int qi = 0; qi < 2; ++qi) {
    const bf16* qp =
        Qt + ((size_t)b * Nn + qbase + qi * 16 + lm) * Ee + h * HD + quad * 8;
    qf[qi][0] = *(const bf16x8*)qp;
    qf[qi][1] = *(const bf16x8*)(qp + 32);
  }
  floatx4 accO[2][4];
#pragma unroll
  for (int qi = 0; qi < 2; ++qi)
#pragma unroll
    for (int df = 0; df < 4; ++df) accO[qi][df] = (floatx4){0.f, 0.f, 0.f, 0.f};
  float lsum[2] = {0.f, 0.f};

  // staging: r0 = tid>>3 in [0,32), g = tid&7; rows r0 and r0+32
  const int r0 = tid >> 3, g = tid & 7;
  const bf16* kp0 = Kt + ((size_t)b * Nn + r0) * Ee + h * HD + g * 8;
  const bf16* kp1 = kp0 + (size_t)32 * Ee;
  const bf16* vp0 = Ve + ((size_t)b * Ee + h * HD + r0) * Nn + g * 8;
  const bf16* vp1 = vp0 + (size_t)32 * Nn;

  // prologue: tile 0 -> buf 0
  bf16x8 ka = *(const bf16x8*)kp0;
  bf16x8 kb = *(const bf16x8*)kp1;
  bf16x8 va = *(const bf16x8*)vp0;
  bf16x8 vb = *(const bf16x8*)vp1;
  kp0 += (size_t)64 * Ee; kp1 += (size_t)64 * Ee;
  vp0 += 64; vp1 += 64;
  *(bf16x8*)&Ks[0][r0 * SK + g * 8] = ka;
  *(bf16x8*)&Ks[0][(r0 + 32) * SK + g * 8] = kb;
  *(bf16x8*)&Vs[0][r0 * SK + g * 8] = va;
  *(bf16x8*)&Vs[0][(r0 + 32) * SK + g * 8] = vb;
  __syncthreads();

#pragma unroll 1
  for (int kt = 0; kt <= last; ++kt) {
    const int c = kt & 1;
    const int k0 = kt * 64;
    const bool more = kt < last;
    if (more) {                       // prefetch next tile (hidden under QK)
      ka = *(const bf16x8*)kp0;
      kb = *(const bf16x8*)kp1;
      va = *(const bf16x8*)vp0;
      vb = *(const bf16x8*)vp1;
      kp0 += (size_t)64 * Ee; kp1 += (size_t)64 * Ee;
      vp0 += 64; vp1 += 64;
    }
    const bool skip = k0 > qbase + 31;  // wave-uniform: tile fully masked

    floatx4 accS[2][4];
    if (!skip) {
      // S^T = K Q^T : A[key=f*16+lm][e=quad*8+j+ks*32] from Ks, shared by qi
#pragma unroll
      for (int qi = 0; qi < 2; ++qi)
#pragma unroll
        for (int f = 0; f < 4; ++f) accS[qi][f] = (floatx4){0.f, 0.f, 0.f, 0.f};
#pragma unroll
      for (int ks = 0; ks < 2; ++ks)
#pragma unroll
        for (int f = 0; f < 4; ++f) {
          bf16x8 ak =
              *(const bf16x8*)&Ks[c][(f * 16 + lm) * SK + ks * 32 + quad * 8];
#pragma unroll
          for (int qi = 0; qi < 2; ++qi)
            accS[qi][f] = __builtin_amdgcn_mfma_f32_16x16x32_bf16(
                ak, qf[qi][ks], accS[qi][f], 0, 0, 0);
        }
    }
    if (more) {                       // stage prefetched tile into other buf
      *(bf16x8*)&Ks[c ^ 1][r0 * SK + g * 8] = ka;
      *(bf16x8*)&Ks[c ^ 1][(r0 + 32) * SK + g * 8] = kb;
      *(bf16x8*)&Vs[c ^ 1][r0 * SK + g * 8] = va;
      *(bf16x8*)&Vs[c ^ 1][(r0 + 32) * SK + g * 8] = vb;
    }
    if (!skip) {
      // softmax + pack: key = k0 + cc*16 + quad*4 + r, q = qbase + qi*16 + lm
      const bool maskt = (k0 + 63 > qbase);
      short4v pb[2][4];
#pragma unroll
      for (int qi = 0; qi < 2; ++qi) {
        const int qg = qbase + qi * 16 + lm;
#pragma unroll
        for (int f = 0; f < 4; ++f) {
          union { bf16 h4[4]; short4v s; } u;
#pragma unroll
          for (int r = 0; r < 4; ++r) {
            float pv = __builtin_exp2f(accS[qi][f][r] - SHIFT);
            if (maskt && (k0 + f * 16 + quad * 4 + r) > qg) pv = 0.f;
            bf16 pbv = (bf16)pv;
            lsum[qi] += (float)pbv;
            u.h4[r] = pbv;
          }
          pb[qi][f] = u.s;
        }
      }
      // O^T += V^T P^T : A[d=df*16+lm][key=cc*16+quad*4+j] from Vs (b64),
      // each V read shared by both qi
#pragma unroll
      for (int cc = 0; cc < 4; ++cc) {
#pragma unroll
        for (int df = 0; df < 4; ++df) {
          union { bf16x4 bv4; short4v s; } cv;
          cv.bv4 = *(const bf16x4*)&Vs[c][(df * 16 + lm) * SK + cc * 16 + quad * 4];
#pragma unroll
          for (int qi = 0; qi < 2; ++qi)
            accO[qi][df] = __builtin_amdgcn_mfma_f32_16x16x16bf16_1k(
                cv.s, pb[qi][cc], accO[qi][df], 0, 0, 0);
        }
      }
    }
    __syncthreads();  // buf c reads done everywhere; buf c^1 fully staged
  }

  // l(q) split across the 4 quads -> reduce lanes lm+16k
#pragma unroll
  for (int qi = 0; qi < 2; ++qi) {
    lsum[qi] += __shfl_xor(lsum[qi], 16);
    lsum[qi] += __shfl_xor(lsum[qi], 32);
  }

  // epilogue: accO[qi][df] rows d = df*16+quad*4+r, col q = qbase+qi*16+lm
#pragma unroll
  for (int qi = 0; qi < 2; ++qi) {
    const float inv = 1.0f / lsum[qi];
    const int qg = qbase + qi * 16 + lm;
#pragma unroll
    for (int df = 0; df < 4; ++df) {
#pragma unroll
      for (int r = 0; r < 4; ++r) {
        int d = h * HD + df * 16 + quad * 4 + r;
        size_t off = ((size_t)b * Ee + d) * Nn + qg;
        if (!f32) ((bf16*)Out)[off] = (bf16)(accO[qi][df][r] * inv);
        else      ((float*)Out)[off] = accO[qi][df][r] * inv;
      }
    }
  }
}

// ---------------------------------------------------------------- launch
extern "C" void kernel_launch(void* const* d_in, const int* in_sizes, int n_in,
                              void* d_out, int out_size, void* d_ws,
                              size_t ws_size, hipStream_t stream) {
  const void* q  = d_in[0];
  const void* k  = d_in[1];
  const void* Wq = d_in[2];
  const void* bq = d_in[3];
  const void* Wk = d_in[4];
  const void* bk = d_in[5];
  const void* Wv = d_in[6];
  const void* bv = d_in[7];

  const size_t SZ = (size_t)B_ * Nn * Cc;  // 4M elems = 8MB bf16 per region
  // ws: [flag 1KB][Xtq 8MB][Qt 8MB][Kt 8MB].
  // d_out (16MB when fp32): lower 8MB = Xtk scratch, upper 8MB = bf16 W/bias
  // copies (only written when flag=1, i.e. when the buffer is 16MB).
  int*  flag = (int*)d_ws;
  bf16* Xtq  = (bf16*)((char*)d_ws + 1024);
  bf16* Qt   = Xtq + SZ;
  bf16* Kt   = Qt + SZ;
  bf16* Xtk  = (bf16*)d_out;                          // dead before attn writes
  bf16* Vh   = Xtq;                                   // V e-major (B,E,N)
  bf16* Wb   = (bf16*)((char*)d_out + 8 * 1024 * 1024);
  bf16* Wqb = Wb,            *Wkb = Wb + WSEG,        *Wvb = Wb + 2 * WSEG;
  bf16* bqb = Wb + 3 * WSEG, *bkb = bqb + 512,        *bvb = bqb + 1024;

  detect_dtype<<<1, 64, 0, stream>>>((const unsigned short*)Wq, flag);
  wcvt<<<(WTOT / 8 + 255) / 256, 256, 0, stream>>>(
      (const float*)Wq, (const float*)Wk, (const float*)Wv,
      (const float*)bq, (const float*)bk, (const float*)bv, Wb, flag);
  transpose_k<<<dim3(64, 8, 4), 256, 0, stream>>>(q, k, Xtq, Xtk, flag);
  gemm_bt<<<dim3(32, 8, 2), 256, 0, stream>>>(
      Xtq, Xtq, (long)Nn * Cc, Wq, Wqb, 0L, bq, bqb,
      Qt, (long)Nn * Ee, Ee, 0, QSCALE, flag);
  gemm_bt<<<dim3(32, 8, 2), 256, 0, stream>>>(
      Xtk, Xtk, (long)Nn * Cc, Wk, Wkb, 0L, bk, bkb,
      Kt, (long)Nn * Ee, Ee, 0, 1.0f, flag);
  gemm_bt<<<dim3(4, 64, 2), 256, 0, stream>>>(
      Wv, Wvb, 0L, Xtk, Xtk, (long)Nn * Cc, bv, bvb,
      Vh, (long)Ee * Nn, Nn, 1, 1.0f, flag);
  attn<<<dim3(32, NH, B_), 256, 0, stream>>>(Qt, Kt, Vh, d_out, flag);
}